// Round 4
// baseline (642.569 us; speedup 1.0000x reference)
//
#include <hip/hip_runtime.h>
#include <cstdint>
#include <cstddef>

#define Bb 128
#define Tt 2048
#define Dd 512
#define Hh 512
#define Mtot (Bb*Tt)

typedef __attribute__((ext_vector_type(8))) _Float16 h8;
typedef __attribute__((ext_vector_type(4))) float f4;

// ---------------- kernel 1: W -> fp16 ----------------
__global__ void w16_kernel(const float* __restrict__ W, _Float16* __restrict__ W16) {
    int i = blockIdx.x * 256 + threadIdx.x;
    W16[i] = (_Float16)W[i];
}

// ---------------- kernel 1b: mask compaction (deterministic prefix-sum) ------
__global__ void compact_kernel(const int* __restrict__ mask, int* __restrict__ cidx,
                               int* __restrict__ cnt) {
    __shared__ int wsum[4];
    int b = blockIdx.x, tid = threadIdx.x;  // 256 threads
    const int* mrow = mask + (size_t)b * Tt;
    int mv[8], c = 0;
#pragma unroll
    for (int i = 0; i < 8; i++) { mv[i] = mrow[tid * 8 + i]; c += mv[i]; }
    int lane = tid & 63, wv = tid >> 6;
    int inc = c;
#pragma unroll
    for (int off = 1; off < 64; off <<= 1) {
        int n = __shfl_up(inc, off);
        if (lane >= off) inc += n;
    }
    if (lane == 63) wsum[wv] = inc;
    __syncthreads();
    int wbase = 0;
    for (int w = 0; w < wv; w++) wbase += wsum[w];
    int pos = wbase + inc - c;  // exclusive prefix
    int* crow = cidx + (size_t)b * Tt;
#pragma unroll
    for (int i = 0; i < 8; i++)
        if (mv[i]) crow[pos++] = tid * 8 + i;
    if (tid == 255) cnt[b] = wbase + inc;
}

// ---------------- kernel 2: col_t = relu(col @ W^T), fp32 exact ----------------
__global__ void col_proj_kernel(const float* __restrict__ col, const float* __restrict__ W,
                                float* __restrict__ colt) {
    __shared__ float c[Dd];
    int b = blockIdx.x;
    int tid = threadIdx.x;  // 128 threads
    for (int i = tid; i < Dd; i += 128) c[i] = col[b * Dd + i];
    __syncthreads();
    int h = blockIdx.y * 128 + tid;
    const f4* w4 = (const f4*)(W + (size_t)h * Dd);
    float acc = 0.f;
#pragma unroll 8
    for (int k = 0; k < Dd / 4; k++) {
        f4 w = w4[k];
        acc += w.x * c[4 * k] + w.y * c[4 * k + 1] + w.z * c[4 * k + 2] + w.w * c[4 * k + 3];
    }
    colt[b * Hh + h] = fmaxf(acc, 0.f);
}

// ---------------- kernel 3: BARRIER-FREE fused scores GEMM ----------------
// 256 threads = 4 waves. Block handles 32 compacted rows; wave w owns the
// 32x128 output strip [rows r0..r0+31] x [cols w*128..w*128+127].
// No LDS staging, no in-loop barriers: A gathered global->reg + in-reg fp16
// hi/lo split; B (W16) global->reg. One barrier in the epilogue reduction.
__global__ __launch_bounds__(256) void scores_kernel(
    const float* __restrict__ X,        // [B*T][512]
    const _Float16* __restrict__ W16,   // [512][512]
    const float* __restrict__ colt,     // [128][512]
    const int* __restrict__ cidx,       // [B][T] compacted t-indices
    const int* __restrict__ cnt,        // [B]
    float* __restrict__ scores)         // [B*T], pre-zeroed
{
    const int tid = threadIdx.x;
    const int b = blockIdx.x >> 6;      // 64 tiles per b
    const int tile = blockIdx.x & 63;
    const int count = cnt[b];
    const int r0 = tile * 32;
    if (r0 >= count) return;            // uniform early-exit (before any barrier)

    __shared__ float sred[4][32];       // 512B, epilogue only

    const int wave = tid >> 6;          // 0..3 : N-strip
    const int lane = tid & 63;
    const int l16 = lane & 15;
    const int khi = lane >> 4;          // 0..3 : k-subchunk (8 elems)

    // Per-lane A row pointers (gathered, clamped to stay in-bounds).
    const int* crow = cidx + (size_t)b * Tt;
    const int rl0 = r0 + l16;
    const int rl1 = r0 + 16 + l16;
    const int t0i = crow[rl0 < count ? rl0 : count - 1];
    const int t1i = crow[rl1 < count ? rl1 : count - 1];
    const float* xr0 = X + ((size_t)b * Tt + t0i) * Dd + khi * 8;
    const float* xr1 = X + ((size_t)b * Tt + t1i) * Dd + khi * 8;

    // Per-lane B base: row = wave*128 + nr*16 + l16, elem offset khi*8.
    const _Float16* wbase = W16 + ((size_t)(wave * 128 + l16)) * Dd + khi * 8;

    f4 acc[2][8];
#pragma unroll
    for (int i = 0; i < 2; i++)
#pragma unroll
        for (int j = 0; j < 8; j++) {
            f4 z = {0.f, 0.f, 0.f, 0.f};
            acc[i][j] = z;
        }

#pragma unroll 4
    for (int ks = 0; ks < 16; ks++) {
        const int k0 = ks * 32;
        // ---- A: 8 fp32 per mr, in-reg hi/lo fp16 split ----
        float4 a0a = *(const float4*)(xr0 + k0);
        float4 a0b = *(const float4*)(xr0 + k0 + 4);
        float4 a1a = *(const float4*)(xr1 + k0);
        float4 a1b = *(const float4*)(xr1 + k0 + 4);
        float a0[8] = {a0a.x, a0a.y, a0a.z, a0a.w, a0b.x, a0b.y, a0b.z, a0b.w};
        float a1[8] = {a1a.x, a1a.y, a1a.z, a1a.w, a1b.x, a1b.y, a1b.z, a1b.w};
        h8 ah0, al0, ah1, al1;
#pragma unroll
        for (int j = 0; j < 8; j++) {
            _Float16 h0 = (_Float16)a0[j];
            _Float16 h1 = (_Float16)a1[j];
            ah0[j] = h0; al0[j] = (_Float16)(a0[j] - (float)h0);
            ah1[j] = h1; al1[j] = (_Float16)(a1[j] - (float)h1);
        }
        // ---- B direct + MFMA ----
#pragma unroll
        for (int nr = 0; nr < 8; nr++) {
            h8 bf = *(const h8*)(wbase + (size_t)nr * 16 * Dd + k0);
            acc[0][nr] = __builtin_amdgcn_mfma_f32_16x16x32_f16(ah0, bf, acc[0][nr], 0, 0, 0);
            acc[1][nr] = __builtin_amdgcn_mfma_f32_16x16x32_f16(ah1, bf, acc[1][nr], 0, 0, 0);
            acc[0][nr] = __builtin_amdgcn_mfma_f32_16x16x32_f16(al0, bf, acc[0][nr], 0, 0, 0);
            acc[1][nr] = __builtin_amdgcn_mfma_f32_16x16x32_f16(al1, bf, acc[1][nr], 0, 0, 0);
        }
    }

    // ---- epilogue: relu * colt, reduce across the wave's 128 cols ----
    float rs[2][4];
#pragma unroll
    for (int mr = 0; mr < 2; mr++)
#pragma unroll
        for (int r = 0; r < 4; r++) rs[mr][r] = 0.f;

#pragma unroll
    for (int nr = 0; nr < 8; nr++) {
        float cv = colt[b * Hh + wave * 128 + nr * 16 + l16];
#pragma unroll
        for (int mr = 0; mr < 2; mr++)
#pragma unroll
            for (int r = 0; r < 4; r++)
                rs[mr][r] += fmaxf(acc[mr][nr][r], 0.f) * cv;
    }
#pragma unroll
    for (int mr = 0; mr < 2; mr++)
#pragma unroll
        for (int r = 0; r < 4; r++) {
            float v = rs[mr][r];
            v += __shfl_xor(v, 1);
            v += __shfl_xor(v, 2);
            v += __shfl_xor(v, 4);
            v += __shfl_xor(v, 8);
            rs[mr][r] = v;
        }
    // C/D layout: row_local = mr*16 + khi*4 + r (col = l16); l16==0 lanes hold sums
    if (l16 == 0) {
#pragma unroll
        for (int mr = 0; mr < 2; mr++)
#pragma unroll
            for (int r = 0; r < 4; r++)
                sred[wave][mr * 16 + khi * 4 + r] = rs[mr][r];
    }
    __syncthreads();
    if (tid < 32) {
        int r = r0 + tid;
        if (r < count) {
            float s = sred[0][tid] + sred[1][tid] + sred[2][tid] + sred[3][tid];
            scores[(size_t)b * Tt + crow[r]] = s;  // mask==1 here
        }
    }
}

// ---------------- kernel 4: softmax per b (IN-PLACE) + copy col into cat ------
__global__ void softmax_kernel(const float* __restrict__ scores, const float* __restrict__ col,
                               float* __restrict__ attn, float* __restrict__ out) {
    __shared__ float sm[256];
    int b = blockIdx.x, tid = threadIdx.x;
    const float* srow = scores + (size_t)b * Tt;
    float v[8];
#pragma unroll
    for (int i = 0; i < 8; i++) v[i] = srow[tid + i * 256];
    float mx = -1e30f;
#pragma unroll
    for (int i = 0; i < 8; i++) mx = fmaxf(mx, v[i]);
    sm[tid] = mx;
    __syncthreads();
    for (int s = 128; s > 0; s >>= 1) {
        if (tid < s) sm[tid] = fmaxf(sm[tid], sm[tid + s]);
        __syncthreads();
    }
    float M = sm[0];
    __syncthreads();
    float e[8];
    float sum = 0.f;
#pragma unroll
    for (int i = 0; i < 8; i++) {
        e[i] = __expf(v[i] - M);
        sum += e[i];
    }
    sm[tid] = sum;
    __syncthreads();
    for (int s = 128; s > 0; s >>= 1) {
        if (tid < s) sm[tid] += sm[tid + s];
        __syncthreads();
    }
    float inv = 1.f / sm[0];
    float* arow = attn + (size_t)b * Tt;
#pragma unroll
    for (int i = 0; i < 8; i++) arow[tid + i * 256] = e[i] * inv;
    for (int d = tid; d < Dd; d += 256) out[(size_t)b * 1024 + d] = col[(size_t)b * Dd + d];
}

// ---------------- kernel 5: partial weighted sums over t (4 chunks of 512) ----
__global__ void wsum_kernel(const float* __restrict__ attn, const float* __restrict__ X,
                            float* __restrict__ part) {
    int dh = blockIdx.x;   // 0..1
    int tc = blockIdx.y;   // 0..3
    int b  = blockIdx.z;   // 0..127
    int tid = threadIdx.x; // 256
    int d = dh * 256 + tid;
    __shared__ float sa[512];
    int t0 = tc * 512;
    sa[tid] = attn[(size_t)b * Tt + t0 + tid];
    sa[tid + 256] = attn[(size_t)b * Tt + t0 + 256 + tid];
    __syncthreads();
    float acc = 0.f;
    const float* xp = X + ((size_t)b * Tt + t0) * Dd + d;
#pragma unroll 4
    for (int j = 0; j < 512; j++) acc += sa[j] * xp[(size_t)j * Dd];
    part[((size_t)b * 4 + tc) * Dd + d] = acc;
}

// ---------------- kernel 6: combine partials, write both outputs ----------------
__global__ void combine_kernel(const float* __restrict__ part, float* __restrict__ out) {
    int i = blockIdx.x * 256 + threadIdx.x;  // < 65536
    int b = i >> 9, d = i & 511;
    float s = 0.f;
#pragma unroll
    for (int tc = 0; tc < 4; tc++) s += part[((size_t)b * 4 + tc) * Dd + d];
    out[(size_t)b * 1024 + 512 + d] = s;                 // cat section, second half
    out[(size_t)Bb * 1024 + (size_t)b * 512 + d] = s;    // attention_output section
}

extern "C" void kernel_launch(void* const* d_in, const int* in_sizes, int n_in,
                              void* d_out, int out_size, void* d_ws, size_t ws_size,
                              hipStream_t stream) {
    const float* col  = (const float*)d_in[0];   // [128,512]
    const float* X    = (const float*)d_in[1];   // [128,2048,512]
    const int*   mask = (const int*)d_in[2];     // [128,2048]
    const float* W    = (const float*)d_in[3];   // [512,512]
    float* out = (float*)d_out;

    // Total ws usage: 3841 KB
    char* ws = (char*)d_ws;
    _Float16* W16   = (_Float16*)ws;                     // 0    .. 512K
    float*    colt  = (float*)(ws + (512 << 10));        // 512K .. 768K
    float*    scores= (float*)(ws + (768 << 10));        // 768K .. 1792K
    float*    attn  = scores;                            // softmax in-place
    float*    part  = (float*)(ws + (1792 << 10));       // 1792K.. 2816K
    int*      cidx  = (int*)(ws + (2816 << 10));         // 2816K.. 3840K
    int*      cnt   = (int*)(ws + (3840 << 10));         // 3840K.. +512B

    hipMemsetAsync(scores, 0, Mtot * sizeof(float), stream);  // masked rows stay 0
    hipLaunchKernelGGL(w16_kernel, dim3(Hh * Dd / 256), dim3(256), 0, stream, W, W16);
    hipLaunchKernelGGL(compact_kernel, dim3(Bb), dim3(256), 0, stream, mask, cidx, cnt);
    hipLaunchKernelGGL(col_proj_kernel, dim3(Bb, Hh / 128), dim3(128), 0, stream, col, W, colt);
    hipLaunchKernelGGL(scores_kernel, dim3(Bb * 64), dim3(256), 0, stream,
                       X, W16, colt, cidx, cnt, scores);
    hipLaunchKernelGGL(softmax_kernel, dim3(Bb), dim3(256), 0, stream, scores, col, attn, out);
    hipLaunchKernelGGL(wsum_kernel, dim3(2, 4, Bb), dim3(256), 0, stream, attn, X, part);
    hipLaunchKernelGGL(combine_kernel, dim3(65536 / 256), dim3(256), 0, stream, part, out);
}

// Round 5
// 373.163 us; speedup vs baseline: 1.7220x; 1.7220x over previous
//
#include <hip/hip_runtime.h>
#include <cstdint>
#include <cstddef>

#define Bb 128
#define Tt 2048
#define Dd 512
#define Hh 512
#define Mtot (Bb*Tt)

typedef __attribute__((ext_vector_type(8))) _Float16 h8;
typedef __attribute__((ext_vector_type(4))) float f4;

// Raw barrier: LDS-ordering only. Deliberately NO vmcnt drain -> global loads
// issued for t+1/t+2 stay in flight across the barrier (T3/T4 essence).
#define PIPE_BARRIER() do { \
    asm volatile("s_waitcnt lgkmcnt(0)" ::: "memory"); \
    __builtin_amdgcn_sched_barrier(0); \
    __builtin_amdgcn_s_barrier(); \
    __builtin_amdgcn_sched_barrier(0); \
    asm volatile("" ::: "memory"); \
} while (0)

__device__ __forceinline__ void cvt8(const float4& a, const float4& b, h8& hi, h8& lo) {
    float s[8] = {a.x, a.y, a.z, a.w, b.x, b.y, b.z, b.w};
#pragma unroll
    for (int j = 0; j < 8; j++) {
        _Float16 h = (_Float16)s[j];
        hi[j] = h;
        lo[j] = (_Float16)(s[j] - (float)h);
    }
}

// ---------------- kernel 1: W -> fp16 ----------------
__global__ void w16_kernel(const float* __restrict__ W, _Float16* __restrict__ W16) {
    int i = blockIdx.x * 256 + threadIdx.x;
    W16[i] = (_Float16)W[i];
}

// ---------------- kernel 1b: mask compaction (deterministic prefix-sum) ------
__global__ void compact_kernel(const int* __restrict__ mask, int* __restrict__ cidx,
                               int* __restrict__ cnt) {
    __shared__ int wsum[4];
    int b = blockIdx.x, tid = threadIdx.x;  // 256 threads
    const int* mrow = mask + (size_t)b * Tt;
    int mv[8], c = 0;
#pragma unroll
    for (int i = 0; i < 8; i++) { mv[i] = mrow[tid * 8 + i]; c += mv[i]; }
    int lane = tid & 63, wv = tid >> 6;
    int inc = c;
#pragma unroll
    for (int off = 1; off < 64; off <<= 1) {
        int n = __shfl_up(inc, off);
        if (lane >= off) inc += n;
    }
    if (lane == 63) wsum[wv] = inc;
    __syncthreads();
    int wbase = 0;
    for (int w = 0; w < wv; w++) wbase += wsum[w];
    int pos = wbase + inc - c;  // exclusive prefix
    int* crow = cidx + (size_t)b * Tt;
#pragma unroll
    for (int i = 0; i < 8; i++)
        if (mv[i]) crow[pos++] = tid * 8 + i;
    if (tid == 255) cnt[b] = wbase + inc;
}

// ---------------- kernel 2: col_t = relu(col @ W^T), fp32 exact ----------------
__global__ void col_proj_kernel(const float* __restrict__ col, const float* __restrict__ W,
                                float* __restrict__ colt) {
    __shared__ float c[Dd];
    int b = blockIdx.x;
    int tid = threadIdx.x;  // 128 threads
    for (int i = tid; i < Dd; i += 128) c[i] = col[b * Dd + i];
    __syncthreads();
    int h = blockIdx.y * 128 + tid;
    const f4* w4 = (const f4*)(W + (size_t)h * Dd);
    float acc = 0.f;
#pragma unroll 8
    for (int k = 0; k < Dd / 4; k++) {
        f4 w = w4[k];
        acc += w.x * c[4 * k] + w.y * c[4 * k + 1] + w.z * c[4 * k + 2] + w.w * c[4 * k + 3];
    }
    colt[b * Hh + h] = fmaxf(acc, 0.f);
}

// ---------------- kernel 3: PIPELINED fused scores GEMM ----------------
// BM=128 rows/block, BN=512 (full), BK=32, 16 K-steps. 8 waves = 2M x 4N,
// wave tile 64x128, acc f4[4][8]. Double-buffered LDS; ONE raw barrier per
// K-step; global loads (via regs) never drained at the barrier -> compiler
// emits counted vmcnt at first use, latency hides under MFMA.
// Hazard audit: at step t we write only buf[(t+1)&1], whose last readers
// finished before barrier(t-1); readers of buf[t&1] are protected because
// its writers passed lgkmcnt(0)+barrier(t-1).
__global__ __launch_bounds__(512, 2) void scores_kernel(
    const float* __restrict__ X,        // [B*T][512]
    const _Float16* __restrict__ W16,   // [512][512]
    const float* __restrict__ colt,     // [128][512]
    const int* __restrict__ cidx,       // [B][T] compacted t-indices
    const int* __restrict__ cnt,        // [B]
    float* __restrict__ scores)         // [B*T], pre-zeroed
{
    const int tid = threadIdx.x;
    const int b = blockIdx.x >> 4;      // 16 tiles per b
    const int tile = blockIdx.x & 15;
    const int count = cnt[b];
    const int r0 = tile * 128;
    if (r0 >= count) return;            // uniform early-exit (before any barrier)

    // LDS layout (bytes): bufW[2] @ 0 / 32768 (each 512 rows x 64B, swizzled)
    //                     bufX hi/lo dbuf @ 65536 (each buf 16KB: hi 8KB + lo 8KB)
    //                     sred float[4][128] @ 98304
    __shared__ __align__(16) char lds[100352];
    char* bufXbase = lds + 65536;
    float* sred = (float*)(lds + 98304);

    const int wave = tid >> 6;
    const int lane = tid & 63;
    const int wm = wave >> 2;   // 0..1 : M-half
    const int wn = wave & 3;    // 0..3 : N-strip
    const int l16 = lane & 15;
    const int khi = lane >> 4;  // 0..3

    // ---- W staging: thread stages row `tid`, 4 x 16B chunks, XOR swizzle ----
    const _Float16* W16g = W16 + (size_t)tid * Dd;
    const int wswz = (tid >> 1) & 3;
    const int woff0 = tid * 64 + ((0 ^ wswz) << 4);
    const int woff1 = tid * 64 + ((1 ^ wswz) << 4);
    const int woff2 = tid * 64 + ((2 ^ wswz) << 4);
    const int woff3 = tid * 64 + ((3 ^ wswz) << 4);

    // ---- X staging: thread -> (row = tid>>2, kg = tid&3), 8 floats ----
    const int xrow = tid >> 2, kg = tid & 3;
    const int* crow = cidx + (size_t)b * Tt;
    int rl = r0 + xrow; if (rl >= count) rl = count - 1;   // clamp (dup row, discarded)
    const float* xsrc = X + ((size_t)b * Tt + crow[rl]) * Dd + kg * 8;
    const int xoff = xrow * 64 + ((kg ^ ((xrow >> 1) & 3)) << 4);

    f4 acc[4][8];
#pragma unroll
    for (int i = 0; i < 4; i++)
#pragma unroll
        for (int j = 0; j < 8; j++) {
            f4 z = {0.f, 0.f, 0.f, 0.f};
            acc[i][j] = z;
        }

    float4 xu0, xu1;  // X_{t+1} regs (consumed at step t's write phase)

    // ---- prologue: stage tile 0 into buf0; issue X_1 loads ----
    {
        const uint4* ws = (const uint4*)W16g;
        uint4 w0 = ws[0], w1 = ws[1], w2 = ws[2], w3 = ws[3];
        float4 p0 = *(const float4*)(xsrc);
        float4 p1 = *(const float4*)(xsrc + 4);
        xu0 = *(const float4*)(xsrc + 32);   // X_1 in flight across barrier
        xu1 = *(const float4*)(xsrc + 36);
        char* wW = lds;  // bufW[0]
        *(uint4*)(wW + woff0) = w0;
        *(uint4*)(wW + woff1) = w1;
        *(uint4*)(wW + woff2) = w2;
        *(uint4*)(wW + woff3) = w3;
        h8 hi, lo;
        cvt8(p0, p1, hi, lo);
        char* wXhi = bufXbase;               // bufX[0]
        *(h8*)(wXhi + xoff) = hi;
        *(h8*)(wXhi + 8192 + xoff) = lo;
        PIPE_BARRIER();
    }

    for (int t = 0; t < 16; ++t) {
        const int cur = t & 1;
        // clamped prefetch indices keep the loop body uniform (junk prefetch
        // at the tail is written to the dead buffer / never consumed)
        const int kW = (t < 15 ? t + 1 : 15) * 32;
        const int kX = (t < 14 ? t + 2 : 15) * 32;

        // ---- issue phase: W_{t+1} -> regs, X_{t+2} -> regs ----
        const uint4* ws = (const uint4*)(W16g + kW);
        uint4 w0 = ws[0], w1 = ws[1], w2 = ws[2], w3 = ws[3];
        float4 xn0 = *(const float4*)(xsrc + kX);
        float4 xn1 = *(const float4*)(xsrc + kX + 4);
        __builtin_amdgcn_sched_barrier(0);   // pin issues before compute

        // ---- compute phase: ds_read frags + 64 MFMA from buf[cur] ----
        char* bW   = lds + cur * 32768;
        char* bXhi = bufXbase + cur * 16384;
        char* bXlo = bXhi + 8192;
        h8 ahi[4], alo[4];
#pragma unroll
        for (int mr = 0; mr < 4; mr++) {
            int row = wm * 64 + mr * 16 + l16;
            int off = row * 64 + ((khi ^ ((row >> 1) & 3)) << 4);
            ahi[mr] = *(const h8*)(bXhi + off);
            alo[mr] = *(const h8*)(bXlo + off);
        }
#pragma unroll
        for (int nr = 0; nr < 8; nr++) {
            int row = wn * 128 + nr * 16 + l16;
            h8 bf = *(const h8*)(bW + row * 64 + ((khi ^ ((row >> 1) & 3)) << 4));
#pragma unroll
            for (int mr = 0; mr < 4; mr++) {
                acc[mr][nr] = __builtin_amdgcn_mfma_f32_16x16x32_f16(ahi[mr], bf, acc[mr][nr], 0, 0, 0);
                acc[mr][nr] = __builtin_amdgcn_mfma_f32_16x16x32_f16(alo[mr], bf, acc[mr][nr], 0, 0, 0);
            }
        }

        // ---- write phase: stage t+1 into buf[cur^1] (compiler waits vmcnt) ----
        char* wW = lds + (cur ^ 1) * 32768;
        *(uint4*)(wW + woff0) = w0;
        *(uint4*)(wW + woff1) = w1;
        *(uint4*)(wW + woff2) = w2;
        *(uint4*)(wW + woff3) = w3;
        h8 hi, lo;
        cvt8(xu0, xu1, hi, lo);
        char* wXhi = bufXbase + (cur ^ 1) * 16384;
        *(h8*)(wXhi + xoff) = hi;
        *(h8*)(wXhi + 8192 + xoff) = lo;
        PIPE_BARRIER();

        xu0 = xn0; xu1 = xn1;   // rotate X prefetch regs
    }

    // ---- epilogue: relu * colt, reduce over N ----
    float rs[4][4];
#pragma unroll
    for (int mr = 0; mr < 4; mr++)
#pragma unroll
        for (int r = 0; r < 4; r++) rs[mr][r] = 0.f;

#pragma unroll
    for (int nr = 0; nr < 8; nr++) {
        float cv = colt[b * Hh + wn * 128 + nr * 16 + l16];
#pragma unroll
        for (int mr = 0; mr < 4; mr++)
#pragma unroll
            for (int r = 0; r < 4; r++)
                rs[mr][r] += fmaxf(acc[mr][nr][r], 0.f) * cv;
    }
#pragma unroll
    for (int mr = 0; mr < 4; mr++)
#pragma unroll
        for (int r = 0; r < 4; r++) {
            float v = rs[mr][r];
            v += __shfl_xor(v, 1);
            v += __shfl_xor(v, 2);
            v += __shfl_xor(v, 4);
            v += __shfl_xor(v, 8);
            rs[mr][r] = v;
        }
    // C/D layout: local row = wm*64 + mr*16 + khi*4 + r; col = l16
    if (l16 == 0) {
#pragma unroll
        for (int mr = 0; mr < 4; mr++)
#pragma unroll
            for (int r = 0; r < 4; r++)
                sred[wn * 128 + wm * 64 + mr * 16 + khi * 4 + r] = rs[mr][r];
    }
    __syncthreads();
    if (tid < 128) {
        int r = r0 + tid;
        if (r < count) {
            float s = sred[tid] + sred[128 + tid] + sred[256 + tid] + sred[384 + tid];
            scores[(size_t)b * Tt + crow[r]] = s;  // mask==1 here
        }
    }
}

// ---------------- kernel 4: softmax per b (IN-PLACE) + copy col into cat ------
__global__ void softmax_kernel(const float* __restrict__ scores, const float* __restrict__ col,
                               float* __restrict__ attn, float* __restrict__ out) {
    __shared__ float sm[256];
    int b = blockIdx.x, tid = threadIdx.x;
    const float* srow = scores + (size_t)b * Tt;
    float v[8];
#pragma unroll
    for (int i = 0; i < 8; i++) v[i] = srow[tid + i * 256];
    float mx = -1e30f;
#pragma unroll
    for (int i = 0; i < 8; i++) mx = fmaxf(mx, v[i]);
    sm[tid] = mx;
    __syncthreads();
    for (int s = 128; s > 0; s >>= 1) {
        if (tid < s) sm[tid] = fmaxf(sm[tid], sm[tid + s]);
        __syncthreads();
    }
    float M = sm[0];
    __syncthreads();
    float e[8];
    float sum = 0.f;
#pragma unroll
    for (int i = 0; i < 8; i++) {
        e[i] = __expf(v[i] - M);
        sum += e[i];
    }
    sm[tid] = sum;
    __syncthreads();
    for (int s = 128; s > 0; s >>= 1) {
        if (tid < s) sm[tid] += sm[tid + s];
        __syncthreads();
    }
    float inv = 1.f / sm[0];
    float* arow = attn + (size_t)b * Tt;
#pragma unroll
    for (int i = 0; i < 8; i++) arow[tid + i * 256] = e[i] * inv;
    for (int d = tid; d < Dd; d += 256) out[(size_t)b * 1024 + d] = col[(size_t)b * Dd + d];
}

// ---------------- kernel 5: partial weighted sums over t (4 chunks of 512) ----
__global__ void wsum_kernel(const float* __restrict__ attn, const float* __restrict__ X,
                            float* __restrict__ part) {
    int dh = blockIdx.x;   // 0..1
    int tc = blockIdx.y;   // 0..3
    int b  = blockIdx.z;   // 0..127
    int tid = threadIdx.x; // 256
    int d = dh * 256 + tid;
    __shared__ float sa[512];
    int t0 = tc * 512;
    sa[tid] = attn[(size_t)b * Tt + t0 + tid];
    sa[tid + 256] = attn[(size_t)b * Tt + t0 + 256 + tid];
    __syncthreads();
    float acc = 0.f;
    const float* xp = X + ((size_t)b * Tt + t0) * Dd + d;
#pragma unroll 4
    for (int j = 0; j < 512; j++) acc += sa[j] * xp[(size_t)j * Dd];
    part[((size_t)b * 4 + tc) * Dd + d] = acc;
}

// ---------------- kernel 6: combine partials, write both outputs ----------------
__global__ void combine_kernel(const float* __restrict__ part, float* __restrict__ out) {
    int i = blockIdx.x * 256 + threadIdx.x;  // < 65536
    int b = i >> 9, d = i & 511;
    float s = 0.f;
#pragma unroll
    for (int tc = 0; tc < 4; tc++) s += part[((size_t)b * 4 + tc) * Dd + d];
    out[(size_t)b * 1024 + 512 + d] = s;                 // cat section, second half
    out[(size_t)Bb * 1024 + (size_t)b * 512 + d] = s;    // attention_output section
}

extern "C" void kernel_launch(void* const* d_in, const int* in_sizes, int n_in,
                              void* d_out, int out_size, void* d_ws, size_t ws_size,
                              hipStream_t stream) {
    const float* col  = (const float*)d_in[0];   // [128,512]
    const float* X    = (const float*)d_in[1];   // [128,2048,512]
    const int*   mask = (const int*)d_in[2];     // [128,2048]
    const float* W    = (const float*)d_in[3];   // [512,512]
    float* out = (float*)d_out;

    // Total ws usage: 3841 KB
    char* ws = (char*)d_ws;
    _Float16* W16   = (_Float16*)ws;                     // 0    .. 512K
    float*    colt  = (float*)(ws + (512 << 10));        // 512K .. 768K
    float*    scores= (float*)(ws + (768 << 10));        // 768K .. 1792K
    float*    attn  = scores;                            // softmax in-place
    float*    part  = (float*)(ws + (1792 << 10));       // 1792K.. 2816K
    int*      cidx  = (int*)(ws + (2816 << 10));         // 2816K.. 3840K
    int*      cnt   = (int*)(ws + (3840 << 10));         // 3840K.. +512B

    hipMemsetAsync(scores, 0, Mtot * sizeof(float), stream);  // masked rows stay 0
    hipLaunchKernelGGL(w16_kernel, dim3(Hh * Dd / 256), dim3(256), 0, stream, W, W16);
    hipLaunchKernelGGL(compact_kernel, dim3(Bb), dim3(256), 0, stream, mask, cidx, cnt);
    hipLaunchKernelGGL(col_proj_kernel, dim3(Bb, Hh / 128), dim3(128), 0, stream, col, W, colt);
    hipLaunchKernelGGL(scores_kernel, dim3(Bb * 16), dim3(512), 0, stream,
                       X, W16, colt, cidx, cnt, scores);
    hipLaunchKernelGGL(softmax_kernel, dim3(Bb), dim3(256), 0, stream, scores, col, attn, out);
    hipLaunchKernelGGL(wsum_kernel, dim3(2, 4, Bb), dim3(256), 0, stream, attn, X, part);
    hipLaunchKernelGGL(combine_kernel, dim3(65536 / 256), dim3(256), 0, stream, part, out);
}